// Round 5
// baseline (171.490 us; speedup 1.0000x reference)
//
#include <hip/hip_runtime.h>

#define B_    4
#define TE_   256
#define TD_   256
#define DE_   512

// tanh(x) = (e^{2x}-1)/(e^{2x}+1); __expf -> v_mul+v_exp_f32, rcpf -> v_rcp_f32.
// |x| <= ~12 for this data (Gaussian); exp2 overflow needs |x|>44 -> safe.
__device__ __forceinline__ float fast_tanh(float x) {
  float ex = __expf(x + x);
  return (ex - 1.0f) * __builtin_amdgcn_rcpf(ex + 1.0f);
}

// C[M,512] = A[M,512] @ Bm[512,512]; z=0: Uh = enc@Ua, z=1: Ws = dec@Wa.
// 64x64 tile, BK=16, 256 threads, 4x4 micro-tile. As/Bs padded to 68
// (17*16B rows: float4-aligned LDS reads, write conflicts capped at 4-way).
__global__ __launch_bounds__(256) void gemm_uw(
    const float* __restrict__ enc, const float* __restrict__ dec,
    const float* __restrict__ Ua, const float* __restrict__ Wa,
    float* __restrict__ Uh, float* __restrict__ Ws) {
  const float* A; const float* Bm; float* C;
  if (blockIdx.z == 0) { A = enc; Bm = Ua; C = Uh; }
  else                 { A = dec; Bm = Wa; C = Ws; }
  const int K = DE_, N = DE_;
  __shared__ float As[16][68];   // [k][m]
  __shared__ float Bs[16][68];   // [k][n]
  int tid = threadIdx.x;
  int tx = tid & 15, ty = tid >> 4;
  int bm = blockIdx.y * 64, bn = blockIdx.x * 64;
  float acc[4][4] = {};
  for (int k0 = 0; k0 < K; k0 += 16) {
#pragma unroll
    for (int l = 0; l < 4; ++l) {
      int idx = tid + l * 256;
      int am = idx >> 4, ak = idx & 15;          // 16 consecutive k per row
      As[ak][am] = A[(bm + am) * K + k0 + ak];
      int bk = idx >> 6, bn2 = idx & 63;         // 64 consecutive n: coalesced
      Bs[bk][bn2] = Bm[(k0 + bk) * N + bn + bn2];
    }
    __syncthreads();
#pragma unroll
    for (int kk = 0; kk < 16; ++kk) {
      float av[4], bv[4];
#pragma unroll
      for (int i = 0; i < 4; ++i) av[i] = As[kk][ty * 4 + i];
#pragma unroll
      for (int j = 0; j < 4; ++j) bv[j] = Bs[kk][tx * 4 + j];
#pragma unroll
      for (int i = 0; i < 4; ++i)
#pragma unroll
        for (int j = 0; j < 4; ++j)
          acc[i][j] = fmaf(av[i], bv[j], acc[i][j]);
    }
    __syncthreads();
  }
#pragma unroll
  for (int i = 0; i < 4; ++i)
#pragma unroll
    for (int j = 0; j < 4; ++j)
      C[(bm + ty * 4 + i) * N + bn + tx * 4 + j] = acc[i][j];
}

// One block per (b, pair-of-t). 256 threads = 4 waves.
// Phase 1: e[t, 0..255] = V . tanh(Uh[e,:] + Ws[t,:]); wave handles 64 e's,
//          lanes over d (coalesced Uh), shfl_xor reduce. TT=2 amortizes Uh reads.
// Phase 2: block softmax over TE (thread owns one column, both t rows).
// Phase 3: context[t, :] = sum_e attn[e]*enc[e,:]; thread owns 2 columns,
//          enc reads amortized over both t rows.
__global__ __launch_bounds__(256) void fused_attn(
    const float* __restrict__ enc, const float* __restrict__ Uh,
    const float* __restrict__ Ws, const float* __restrict__ Va,
    float* __restrict__ out_ctx, float* __restrict__ out_attn) {
  constexpr int TT = 2;
  int bt = blockIdx.x;
  int b  = bt / (TD_ / TT);
  int t0 = (bt % (TD_ / TT)) * TT;

  __shared__ float ws_s[TT][DE_];
  __shared__ float va_s[DE_];
  __shared__ float e_s[TT][TE_];
  __shared__ float redm[TT][4];
  __shared__ float reds[TT][4];

  int tid = threadIdx.x;
  int lane = tid & 63;
  int wave = tid >> 6;

  const float* ws_row0 = Ws + (size_t)(b * TD_ + t0) * DE_;
#pragma unroll
  for (int i = tid; i < DE_; i += 256) {
    va_s[i]    = Va[i];
    ws_s[0][i] = ws_row0[i];
    ws_s[1][i] = ws_row0[DE_ + i];
  }
  __syncthreads();

  // ---- phase 1: energies ----
  const float* uh_b = Uh + (size_t)b * TE_ * DE_;
  for (int ei = 0; ei < TE_ / 4; ++ei) {
    int e = wave * (TE_ / 4) + ei;
    const float* uh = uh_b + (size_t)e * DE_;
    float acc0 = 0.f, acc1 = 0.f;
#pragma unroll
    for (int d0 = 0; d0 < DE_; d0 += 64) {
      float u = uh[d0 + lane];
      float v = va_s[d0 + lane];
      float x0 = u + ws_s[0][d0 + lane];
      float x1 = u + ws_s[1][d0 + lane];
      acc0 = fmaf(fast_tanh(x0), v, acc0);
      acc1 = fmaf(fast_tanh(x1), v, acc1);
    }
#pragma unroll
    for (int off = 32; off; off >>= 1) {
      acc0 += __shfl_xor(acc0, off);
      acc1 += __shfl_xor(acc1, off);
    }
    if (lane == 0) { e_s[0][e] = acc0; e_s[1][e] = acc1; }
  }
  __syncthreads();

  // ---- phase 2: softmax over encoder axis ----
  float x0 = e_s[0][tid], x1 = e_s[1][tid];
  float m0 = x0, m1 = x1;
#pragma unroll
  for (int off = 32; off; off >>= 1) {
    m0 = fmaxf(m0, __shfl_xor(m0, off));
    m1 = fmaxf(m1, __shfl_xor(m1, off));
  }
  if (lane == 0) { redm[0][wave] = m0; redm[1][wave] = m1; }
  __syncthreads();
  m0 = fmaxf(fmaxf(redm[0][0], redm[0][1]), fmaxf(redm[0][2], redm[0][3]));
  m1 = fmaxf(fmaxf(redm[1][0], redm[1][1]), fmaxf(redm[1][2], redm[1][3]));
  float p0 = __expf(x0 - m0), p1 = __expf(x1 - m1);
  float s0 = p0, s1 = p1;
#pragma unroll
  for (int off = 32; off; off >>= 1) {
    s0 += __shfl_xor(s0, off);
    s1 += __shfl_xor(s1, off);
  }
  if (lane == 0) { reds[0][wave] = s0; reds[1][wave] = s1; }
  __syncthreads();
  s0 = reds[0][0] + reds[0][1] + reds[0][2] + reds[0][3];
  s1 = reds[1][0] + reds[1][1] + reds[1][2] + reds[1][3];
  float a0 = p0 * __builtin_amdgcn_rcpf(s0);
  float a1 = p1 * __builtin_amdgcn_rcpf(s1);
  e_s[0][tid] = a0;
  e_s[1][tid] = a1;
  out_attn[(size_t)(b * TD_ + t0)     * TE_ + tid] = a0;
  out_attn[(size_t)(b * TD_ + t0 + 1) * TE_ + tid] = a1;
  __syncthreads();

  // ---- phase 3: context ----
  const float* enc_b = enc + (size_t)b * TE_ * DE_;
  int cA = tid, cB = tid + 256;
  float c00 = 0.f, c01 = 0.f, c10 = 0.f, c11 = 0.f;
#pragma unroll 4
  for (int e = 0; e < TE_; ++e) {
    float a0v = e_s[0][e], a1v = e_s[1][e];
    float xA = enc_b[(size_t)e * DE_ + cA];
    float xB = enc_b[(size_t)e * DE_ + cB];
    c00 = fmaf(a0v, xA, c00); c01 = fmaf(a0v, xB, c01);
    c10 = fmaf(a1v, xA, c10); c11 = fmaf(a1v, xB, c11);
  }
  float* ctx0 = out_ctx + (size_t)(b * TD_ + t0) * DE_;
  ctx0[cA]       = c00; ctx0[cB]       = c01;
  ctx0[DE_ + cA] = c10; ctx0[DE_ + cB] = c11;
}

extern "C" void kernel_launch(void* const* d_in, const int* in_sizes, int n_in,
                              void* d_out, int out_size, void* d_ws, size_t ws_size,
                              hipStream_t stream) {
  const float* enc = (const float*)d_in[0];
  const float* dec = (const float*)d_in[1];
  const float* Ua  = (const float*)d_in[2];
  const float* Wa  = (const float*)d_in[3];
  const float* Va  = (const float*)d_in[4];

  float* out_ctx  = (float*)d_out;                       // [B,TD,DE]
  float* out_attn = out_ctx + (size_t)B_ * TD_ * DE_;    // [B,TD,TE]

  float* Uh = (float*)d_ws;                              // [B,TE,DE] f32, 2MB
  float* Ws = Uh + (size_t)B_ * TE_ * DE_;               // [B,TD,DE] f32, 2MB

  dim3 gg(DE_ / 64, (B_ * TE_) / 64, 2);                 // 8 x 16 x 2 = 256 blocks
  gemm_uw<<<gg, 256, 0, stream>>>(enc, dec, Ua, Wa, Uh, Ws);

  fused_attn<<<B_ * TD_ / 2, 256, 0, stream>>>(enc, Uh, Ws, Va, out_ctx, out_attn);
}

// Round 6
// 144.205 us; speedup vs baseline: 1.1892x; 1.1892x over previous
//
#include <hip/hip_runtime.h>

#define B_    4
#define TE_   256
#define TD_   256
#define DE_   512
#define K_    512

typedef __attribute__((ext_vector_type(8))) short bf16x8;
typedef __attribute__((ext_vector_type(4))) float f32x4;

// ---- bf16 helpers (RNE) ----
__device__ __forceinline__ ushort f2bf(float x) {
  uint u = __float_as_uint(x);
  uint r = (u + 0x7fffu + ((u >> 16) & 1u)) >> 16;
  return (ushort)r;
}
__device__ __forceinline__ float bf2f(ushort h) {
  return __uint_as_float(((uint)h) << 16);
}

// tanh(x) = (e^{2x}-1)/(e^{2x}+1)
__device__ __forceinline__ float fast_tanh(float x) {
  float ex = __expf(x + x);
  return (ex - 1.0f) * __builtin_amdgcn_rcpf(ex + 1.0f);
}

// ---- convert enc/dec (row-major, [1024,512]) to hi/lo bf16 ----
// grid (512, 2) x 256 thr; each thread 4 elems (f32x4 load, ushort4 stores).
__global__ __launch_bounds__(256) void conv_hilo(
    const float* __restrict__ enc, const float* __restrict__ dec,
    ushort* __restrict__ ehi, ushort* __restrict__ elo,
    ushort* __restrict__ dhi, ushort* __restrict__ dlo) {
  const float* in = blockIdx.y ? dec : enc;
  ushort* hi = blockIdx.y ? dhi : ehi;
  ushort* lo = blockIdx.y ? dlo : elo;
  int i = (blockIdx.x * 256 + threadIdx.x) * 4;
  float4 v = *(const float4*)&in[i];
  ushort4 h, l;
  h.x = f2bf(v.x); l.x = f2bf(v.x - bf2f(h.x));
  h.y = f2bf(v.y); l.y = f2bf(v.y - bf2f(h.y));
  h.z = f2bf(v.z); l.z = f2bf(v.z - bf2f(h.z));
  h.w = f2bf(v.w); l.w = f2bf(v.w - bf2f(h.w));
  *(ushort4*)&hi[i] = h;
  *(ushort4*)&lo[i] = l;
}

// ---- transpose+convert Ua/Wa [K,N] -> n-major [N,K] hi/lo bf16 ----
// grid (8, 8, 2) x 256 thr, 64x64 tiles via LDS.
__global__ __launch_bounds__(256) void conv_bt(
    const float* __restrict__ Ua, const float* __restrict__ Wa,
    ushort* __restrict__ uhi, ushort* __restrict__ ulo,
    ushort* __restrict__ whi, ushort* __restrict__ wlo) {
  const float* in = blockIdx.z ? Wa : Ua;
  ushort* thi = blockIdx.z ? whi : uhi;
  ushort* tlo = blockIdx.z ? wlo : ulo;
  __shared__ float tile[64][65];
  int k0 = blockIdx.y * 64, n0 = blockIdx.x * 64;
  int tid = threadIdx.x;
#pragma unroll
  for (int i = 0; i < 16; ++i) {
    int idx = tid + i * 256;
    int r = idx >> 6, c = idx & 63;
    tile[r][c] = in[(size_t)(k0 + r) * 512 + n0 + c];
  }
  __syncthreads();
#pragma unroll
  for (int i = 0; i < 16; ++i) {
    int idx = tid + i * 256;
    int rn = idx >> 6, ck = idx & 63;       // rn: n-index, ck: k-index
    float x = tile[ck][rn];
    ushort h = f2bf(x);
    size_t o = (size_t)(n0 + rn) * 512 + k0 + ck;
    thi[o] = h;
    tlo[o] = f2bf(x - bf2f(h));
  }
}

// ---- MFMA split-bf16 GEMM: C[1024,512] = A[1024,512] @ B[512,512] ----
// C = Ahi*Bhi + Ahi*Blo + Alo*Bhi (lo*lo dropped, ~2^-18 rel).
// z=0: enc @ Ua -> Uh ; z=1: dec @ Wa -> Ws. B pre-transposed (n-major).
// 64x64 tile, 4 waves (2x2 wave grid of 32x32), 16x16x32 bf16 MFMA.
// LDS rows padded to 40 ushorts (80B): frag-read bank spread, 16B aligned.
__global__ __launch_bounds__(256) void gemm_mfma(
    const ushort* __restrict__ ehi, const ushort* __restrict__ elo,
    const ushort* __restrict__ dhi, const ushort* __restrict__ dlo,
    const ushort* __restrict__ uhi, const ushort* __restrict__ ulo,
    const ushort* __restrict__ whi, const ushort* __restrict__ wlo,
    float* __restrict__ Uh, float* __restrict__ Ws) {
  const ushort *Ahi, *Alo, *Bhi, *Blo; float* C;
  if (blockIdx.z == 0) { Ahi = ehi; Alo = elo; Bhi = uhi; Blo = ulo; C = Uh; }
  else                 { Ahi = dhi; Alo = dlo; Bhi = whi; Blo = wlo; C = Ws; }
  __shared__ __align__(16) ushort Ah[64 * 40], Al[64 * 40];
  __shared__ __align__(16) ushort Bh[64 * 40], Bl[64 * 40];
  int tid = threadIdx.x;
  int lane = tid & 63, w = tid >> 6;
  int bm = blockIdx.y * 64, bn = blockIdx.x * 64;
  int srow = tid >> 2, sko = (tid & 3) * 8;          // stage: 64 rows x 32 k
  size_t aoff = (size_t)(bm + srow) * K_ + sko;
  size_t boff = (size_t)(bn + srow) * K_ + sko;
  int sdst = srow * 40 + sko;
  int wm = w & 1, wn = w >> 1;
  int frow = lane & 15, fch = (lane >> 4) * 8;       // frag: row, k-chunk
  int ra0 = (wm * 32 + frow) * 40 + fch, ra1 = ra0 + 16 * 40;
  int rb0 = (wn * 32 + frow) * 40 + fch, rb1 = rb0 + 16 * 40;
  f32x4 acc[2][2] = {};
  for (int k0 = 0; k0 < K_; k0 += 32) {
    uint4 vah = *(const uint4*)&Ahi[aoff + k0];
    uint4 val = *(const uint4*)&Alo[aoff + k0];
    uint4 vbh = *(const uint4*)&Bhi[boff + k0];
    uint4 vbl = *(const uint4*)&Blo[boff + k0];
    __syncthreads();                                  // prev-iter reads done
    *(uint4*)&Ah[sdst] = vah;
    *(uint4*)&Al[sdst] = val;
    *(uint4*)&Bh[sdst] = vbh;
    *(uint4*)&Bl[sdst] = vbl;
    __syncthreads();
    bf16x8 ah0 = *(const bf16x8*)&Ah[ra0], ah1 = *(const bf16x8*)&Ah[ra1];
    bf16x8 al0 = *(const bf16x8*)&Al[ra0], al1 = *(const bf16x8*)&Al[ra1];
    bf16x8 bh0 = *(const bf16x8*)&Bh[rb0], bh1 = *(const bf16x8*)&Bh[rb1];
    bf16x8 bl0 = *(const bf16x8*)&Bl[rb0], bl1 = *(const bf16x8*)&Bl[rb1];
    acc[0][0] = __builtin_amdgcn_mfma_f32_16x16x32_bf16(ah0, bh0, acc[0][0], 0, 0, 0);
    acc[0][1] = __builtin_amdgcn_mfma_f32_16x16x32_bf16(ah0, bh1, acc[0][1], 0, 0, 0);
    acc[1][0] = __builtin_amdgcn_mfma_f32_16x16x32_bf16(ah1, bh0, acc[1][0], 0, 0, 0);
    acc[1][1] = __builtin_amdgcn_mfma_f32_16x16x32_bf16(ah1, bh1, acc[1][1], 0, 0, 0);
    acc[0][0] = __builtin_amdgcn_mfma_f32_16x16x32_bf16(ah0, bl0, acc[0][0], 0, 0, 0);
    acc[0][1] = __builtin_amdgcn_mfma_f32_16x16x32_bf16(ah0, bl1, acc[0][1], 0, 0, 0);
    acc[1][0] = __builtin_amdgcn_mfma_f32_16x16x32_bf16(ah1, bl0, acc[1][0], 0, 0, 0);
    acc[1][1] = __builtin_amdgcn_mfma_f32_16x16x32_bf16(ah1, bl1, acc[1][1], 0, 0, 0);
    acc[0][0] = __builtin_amdgcn_mfma_f32_16x16x32_bf16(al0, bh0, acc[0][0], 0, 0, 0);
    acc[0][1] = __builtin_amdgcn_mfma_f32_16x16x32_bf16(al0, bh1, acc[0][1], 0, 0, 0);
    acc[1][0] = __builtin_amdgcn_mfma_f32_16x16x32_bf16(al1, bh0, acc[1][0], 0, 0, 0);
    acc[1][1] = __builtin_amdgcn_mfma_f32_16x16x32_bf16(al1, bh1, acc[1][1], 0, 0, 0);
  }
  // C/D: col = lane&15, row = (lane>>4)*4 + r   [m89-verified]
  int crow = (lane >> 4) * 4, ccol = lane & 15;
#pragma unroll
  for (int i = 0; i < 2; ++i)
#pragma unroll
    for (int j = 0; j < 2; ++j) {
      float* cb = C + (size_t)(bm + wm * 32 + i * 16 + crow) * 512
                    + bn + wn * 32 + j * 16 + ccol;
#pragma unroll
      for (int r = 0; r < 4; ++r) cb[(size_t)r * 512] = acc[i][j][r];
    }
}

// ---- fused energies + softmax + context ----
// 512 blocks x 512 threads (8 waves) -> 2 blocks/CU = 16 waves/CU (50% occ).
// Va + both Ws rows live in registers (no LDS reads in the tanh loop).
__global__ __launch_bounds__(512) void fused_attn(
    const float* __restrict__ enc, const float* __restrict__ Uh,
    const float* __restrict__ Ws, const float* __restrict__ Va,
    float* __restrict__ out_ctx, float* __restrict__ out_attn) {
  int bt = blockIdx.x;
  int b  = bt >> 7;                 // TD_/2 = 128 blocks per batch
  int t0 = (bt & 127) * 2;
  __shared__ float e_s[2][TE_];
  __shared__ float redm[2][4], reds[2][4];
  int tid = threadIdx.x, lane = tid & 63, w = tid >> 6;

  float va_r[8], ws0_r[8], ws1_r[8];
  const float* wsr = Ws + (size_t)(b * TD_ + t0) * DE_;
#pragma unroll
  for (int i = 0; i < 8; ++i) {
    va_r[i]  = Va[i * 64 + lane];
    ws0_r[i] = wsr[i * 64 + lane];
    ws1_r[i] = wsr[DE_ + i * 64 + lane];
  }

  // phase 1: energies; wave w owns e in [w*32, w*32+32)
  const float* uh_b = Uh + (size_t)b * TE_ * DE_;
  for (int ei = 0; ei < 32; ++ei) {
    int e = w * 32 + ei;
    const float* uh = uh_b + (size_t)e * DE_;
    float acc0 = 0.f, acc1 = 0.f;
#pragma unroll
    for (int i = 0; i < 8; ++i) {
      float u = uh[i * 64 + lane];
      acc0 = fmaf(fast_tanh(u + ws0_r[i]), va_r[i], acc0);
      acc1 = fmaf(fast_tanh(u + ws1_r[i]), va_r[i], acc1);
    }
#pragma unroll
    for (int off = 32; off; off >>= 1) {
      acc0 += __shfl_xor(acc0, off);
      acc1 += __shfl_xor(acc1, off);
    }
    if (lane == 0) { e_s[0][e] = acc0; e_s[1][e] = acc1; }
  }
  __syncthreads();

  // phase 2: softmax; waves 0-3 -> t=0, waves 4-7 -> t=1
  int t = tid >> 8, col = tid & 255;
  float x = e_s[t][col];
  float m = x;
#pragma unroll
  for (int off = 32; off; off >>= 1) m = fmaxf(m, __shfl_xor(m, off));
  if (lane == 0) redm[t][w & 3] = m;
  __syncthreads();
  m = fmaxf(fmaxf(redm[t][0], redm[t][1]), fmaxf(redm[t][2], redm[t][3]));
  float p = __expf(x - m);
  float s = p;
#pragma unroll
  for (int off = 32; off; off >>= 1) s += __shfl_xor(s, off);
  if (lane == 0) reds[t][w & 3] = s;
  __syncthreads();
  s = reds[t][0] + reds[t][1] + reds[t][2] + reds[t][3];
  float a = p * __builtin_amdgcn_rcpf(s);
  e_s[t][col] = a;
  out_attn[(size_t)(b * TD_ + t0 + t) * TE_ + col] = a;
  __syncthreads();

  // phase 3: context; thread owns column tid (0..511), both t rows
  const float* enc_b = enc + (size_t)b * TE_ * DE_;
  float c0 = 0.f, c1 = 0.f;
#pragma unroll 4
  for (int e = 0; e < TE_; ++e) {
    float a0v = e_s[0][e], a1v = e_s[1][e];
    float xv = enc_b[(size_t)e * DE_ + tid];
    c0 = fmaf(a0v, xv, c0);
    c1 = fmaf(a1v, xv, c1);
  }
  float* ctx0 = out_ctx + (size_t)(b * TD_ + t0) * DE_;
  ctx0[tid]       = c0;
  ctx0[DE_ + tid] = c1;
}

extern "C" void kernel_launch(void* const* d_in, const int* in_sizes, int n_in,
                              void* d_out, int out_size, void* d_ws, size_t ws_size,
                              hipStream_t stream) {
  const float* enc = (const float*)d_in[0];
  const float* dec = (const float*)d_in[1];
  const float* Ua  = (const float*)d_in[2];
  const float* Wa  = (const float*)d_in[3];
  const float* Va  = (const float*)d_in[4];

  float* out_ctx  = (float*)d_out;                     // [B,TD,DE]
  float* out_attn = out_ctx + (size_t)B_ * TD_ * DE_;  // [B,TD,TE]

  // workspace layout (10 MB total)
  char* wsp = (char*)d_ws;
  float* Uh = (float*)wsp;              wsp += (size_t)B_ * TE_ * DE_ * 4;  // 2MB
  float* Wsm = (float*)wsp;             wsp += (size_t)B_ * TD_ * DE_ * 4;  // 2MB
  ushort* ehi = (ushort*)wsp;           wsp += (size_t)B_ * TE_ * DE_ * 2;  // 1MB
  ushort* elo = (ushort*)wsp;           wsp += (size_t)B_ * TE_ * DE_ * 2;
  ushort* dhi = (ushort*)wsp;           wsp += (size_t)B_ * TD_ * DE_ * 2;
  ushort* dlo = (ushort*)wsp;           wsp += (size_t)B_ * TD_ * DE_ * 2;
  ushort* uhi = (ushort*)wsp;           wsp += (size_t)K_ * DE_ * 2;        // 512KB
  ushort* ulo = (ushort*)wsp;           wsp += (size_t)K_ * DE_ * 2;
  ushort* whi = (ushort*)wsp;           wsp += (size_t)K_ * DE_ * 2;
  ushort* wlo = (ushort*)wsp;           wsp += (size_t)K_ * DE_ * 2;

  conv_hilo<<<dim3(512, 2), 256, 0, stream>>>(enc, dec, ehi, elo, dhi, dlo);
  conv_bt<<<dim3(8, 8, 2), 256, 0, stream>>>(Ua, Wa, uhi, ulo, whi, wlo);
  gemm_mfma<<<dim3(DE_ / 64, (B_ * TE_) / 64, 2), 256, 0, stream>>>(
      ehi, elo, dhi, dlo, uhi, ulo, whi, wlo, Uh, Wsm);
  fused_attn<<<B_ * TD_ / 2, 512, 0, stream>>>(enc, Uh, Wsm, Va, out_ctx, out_attn);
}

// Round 8
// 129.679 us; speedup vs baseline: 1.3224x; 1.1120x over previous
//
#include <hip/hip_runtime.h>

#define B_    4
#define TE_   256
#define TD_   256
#define DE_   512
#define K_    512

typedef __attribute__((ext_vector_type(8))) short bf16x8;
typedef __attribute__((ext_vector_type(4))) float f32x4;

// 2*log2(e): folded into Ua/Wa so tanh arg is ready for exp2.
#define C1F 2.8853900817779268f

__device__ __forceinline__ ushort f2bf(float x) {
  uint u = __float_as_uint(x);
  return (ushort)((u + 0x7fffu + ((u >> 16) & 1u)) >> 16);
}
__device__ __forceinline__ float bf2f(ushort h) {
  return __uint_as_float(((uint)h) << 16);
}
__device__ __forceinline__ float exp2_fast(float x) {
  float r;
  asm("v_exp_f32 %0, %1" : "=v"(r) : "v"(x));
  return r;
}

// ---- enc/dec [1024,512] f32 -> hi/lo bf16 (row-major) ----
__global__ __launch_bounds__(256) void conv_hilo(
    const float* __restrict__ enc, const float* __restrict__ dec,
    ushort* __restrict__ ehi, ushort* __restrict__ elo,
    ushort* __restrict__ dhi, ushort* __restrict__ dlo) {
  const float* in = blockIdx.y ? dec : enc;
  ushort* hi = blockIdx.y ? dhi : ehi;
  ushort* lo = blockIdx.y ? dlo : elo;
  int i = (blockIdx.x * 256 + threadIdx.x) * 4;
  float4 v = *(const float4*)&in[i];
  ushort4 h, l;
  h.x = f2bf(v.x); l.x = f2bf(v.x - bf2f(h.x));
  h.y = f2bf(v.y); l.y = f2bf(v.y - bf2f(h.y));
  h.z = f2bf(v.z); l.z = f2bf(v.z - bf2f(h.z));
  h.w = f2bf(v.w); l.w = f2bf(v.w - bf2f(h.w));
  *(ushort4*)&hi[i] = h;
  *(ushort4*)&lo[i] = l;
}

// ---- C1*Ua, C1*Wa [K,N] -> n-major [N,K] hi/lo bf16 ----
__global__ __launch_bounds__(256) void conv_bt(
    const float* __restrict__ Ua, const float* __restrict__ Wa,
    ushort* __restrict__ uhi, ushort* __restrict__ ulo,
    ushort* __restrict__ whi, ushort* __restrict__ wlo) {
  const float* in = blockIdx.z ? Wa : Ua;
  ushort* thi = blockIdx.z ? whi : uhi;
  ushort* tlo = blockIdx.z ? wlo : ulo;
  __shared__ float tile[64][65];
  int k0 = blockIdx.y * 64, n0 = blockIdx.x * 64;
  int tid = threadIdx.x;
#pragma unroll
  for (int i = 0; i < 16; ++i) {
    int idx = tid + i * 256;
    int r = idx >> 6, c = idx & 63;
    tile[r][c] = in[(size_t)(k0 + r) * 512 + n0 + c];
  }
  __syncthreads();
#pragma unroll
  for (int i = 0; i < 16; ++i) {
    int idx = tid + i * 256;
    int rn = idx >> 6, ck = idx & 63;
    float x = tile[ck][rn] * C1F;           // prescale for exp2
    ushort h = f2bf(x);
    size_t o = (size_t)(n0 + rn) * 512 + k0 + ck;
    thi[o] = h;
    tlo[o] = f2bf(x - bf2f(h));
  }
}

// ---- split-bf16 MFMA GEMM, 32x32 tiles, 1024 blocks ----
// z=0: UhT[d, b*256+e] = (C1*Ua)^T @ enc^T  (A=uhi n-major, B=ehi row-major)
// z=1: Ws [b*256+t, d] = dec @ (C1*Wa)      (A=dhi, B=whi n-major)
// 3-term: hh + hl + lh (lo*lo dropped).
__global__ __launch_bounds__(256) void gemm_mfma(
    const ushort* __restrict__ ehi, const ushort* __restrict__ elo,
    const ushort* __restrict__ dhi, const ushort* __restrict__ dlo,
    const ushort* __restrict__ uhi, const ushort* __restrict__ ulo,
    const ushort* __restrict__ whi, const ushort* __restrict__ wlo,
    float* __restrict__ UhT, float* __restrict__ Ws) {
  const ushort *Ahi, *Alo, *Bhi, *Blo;
  int bid = blockIdx.x, bm, bn;
  if (blockIdx.z == 0) {
    Ahi = uhi; Alo = ulo; Bhi = ehi; Blo = elo;       // M=512(d), N=1024(e)
    bn = (bid & 31) * 32; bm = (bid >> 5) * 32;
  } else {
    Ahi = dhi; Alo = dlo; Bhi = whi; Blo = wlo;       // M=1024(t), N=512(d)
    bn = (bid & 15) * 32; bm = (bid >> 4) * 32;
  }
  __shared__ __align__(16) ushort Ah[32 * 40], Al[32 * 40];
  __shared__ __align__(16) ushort Bh[32 * 40], Bl[32 * 40];
  int tid = threadIdx.x, lane = tid & 63, w = tid >> 6;
  int srow = tid >> 3, sko = (tid & 7) * 4;           // stage 8B per array
  size_t aoff = (size_t)(bm + srow) * K_ + sko;
  size_t boff = (size_t)(bn + srow) * K_ + sko;
  int sdst = srow * 40 + sko;
  int wm = w >> 1, wn = w & 1;
  int frow = lane & 15, fch = (lane >> 4) * 8;
  int ra = (wm * 16 + frow) * 40 + fch;
  int rb = (wn * 16 + frow) * 40 + fch;
  uint2 rah = *(const uint2*)&Ahi[aoff];
  uint2 ral = *(const uint2*)&Alo[aoff];
  uint2 rbh = *(const uint2*)&Bhi[boff];
  uint2 rbl = *(const uint2*)&Blo[boff];
  f32x4 acc = {};
  for (int ks = 0; ks < 16; ++ks) {
    __syncthreads();
    *(uint2*)&Ah[sdst] = rah;
    *(uint2*)&Al[sdst] = ral;
    *(uint2*)&Bh[sdst] = rbh;
    *(uint2*)&Bl[sdst] = rbl;
    __syncthreads();
    if (ks < 15) {                                     // prefetch next k-tile
      size_t ko = (size_t)(ks + 1) * 32;
      rah = *(const uint2*)&Ahi[aoff + ko];
      ral = *(const uint2*)&Alo[aoff + ko];
      rbh = *(const uint2*)&Bhi[boff + ko];
      rbl = *(const uint2*)&Blo[boff + ko];
    }
    bf16x8 ah = *(const bf16x8*)&Ah[ra], al = *(const bf16x8*)&Al[ra];
    bf16x8 bh = *(const bf16x8*)&Bh[rb], bl = *(const bf16x8*)&Bl[rb];
    acc = __builtin_amdgcn_mfma_f32_16x16x32_bf16(ah, bh, acc, 0, 0, 0);
    acc = __builtin_amdgcn_mfma_f32_16x16x32_bf16(ah, bl, acc, 0, 0, 0);
    acc = __builtin_amdgcn_mfma_f32_16x16x32_bf16(al, bh, acc, 0, 0, 0);
  }
  // C/D: col=lane&15, row=(lane>>4)*4+r
  int m0 = bm + wm * 16 + (lane >> 4) * 4;
  int n0 = bn + wn * 16 + (lane & 15);
  if (blockIdx.z == 0) {
    float* cb = UhT + (size_t)(n0 >> 8) * 131072 + (size_t)m0 * 256 + (n0 & 255);
#pragma unroll
    for (int r = 0; r < 4; ++r) cb[(size_t)r * 256] = acc[r];
  } else {
    float* cb = Ws + (size_t)m0 * 512 + n0;
#pragma unroll
    for (int r = 0; r < 4; ++r) cb[(size_t)r * 512] = acc[r];
  }
}

// ---- fused energies + softmax + context ----
// 512 blocks x 512 thr (8 waves). Wave w owns e = w*32+(lane&31) for BOTH t's;
// lane-half splits d-range (0-255 / 256-511), one shfl_xor(32) combines.
// Energy: e~ = sum mv[d] * rcp(1 + 2^(u'+w')),  mv = -2*Va  (softmax-invariant
// shift of true e by sum(Va); attn identical).
__global__ __launch_bounds__(512) void fused_attn(
    const float* __restrict__ enc, const float* __restrict__ UhT,
    const float* __restrict__ Ws, const float* __restrict__ Va,
    float* __restrict__ out_ctx, float* __restrict__ out_attn) {
  int bt = blockIdx.x;
  int b  = bt >> 7;
  int t0 = (bt & 127) * 2;
  __shared__ float ws0_s[DE_], ws1_s[DE_], mv_s[DE_];
  __shared__ float e_s[2][TE_];
  __shared__ float att2[TE_ * 2];          // [e][t] packed pairs
  __shared__ float redm[2][4], reds[2][4];
  int tid = threadIdx.x, lane = tid & 63, w = tid >> 6;

  const float* wsr = Ws + (size_t)(b * TD_ + t0) * DE_;
  ws0_s[tid] = wsr[tid];
  ws1_s[tid] = wsr[DE_ + tid];
  mv_s[tid]  = -2.0f * Va[tid];
  __syncthreads();

  // ---- phase 1: energies (lane owns e, halves split d) ----
  int half = lane >> 5, sub = lane & 31;
  int e = w * 32 + sub;
  const float* up = UhT + (size_t)b * 131072 + (size_t)half * 65536 + e;
  int dbase = half * 256;
  float acc0 = 0.f, acc1 = 0.f;
#pragma unroll 8
  for (int d0 = 0; d0 < 256; d0 += 4) {
    int dd = dbase + d0;
    float4 wv0 = *(const float4*)&ws0_s[dd];
    float4 wv1 = *(const float4*)&ws1_s[dd];
    float4 mv4 = *(const float4*)&mv_s[dd];
#pragma unroll
    for (int j = 0; j < 4; ++j) {
      float u = up[(d0 + j) * 256];
      float w0 = j == 0 ? wv0.x : j == 1 ? wv0.y : j == 2 ? wv0.z : wv0.w;
      float w1 = j == 0 ? wv1.x : j == 1 ? wv1.y : j == 2 ? wv1.z : wv1.w;
      float mv = j == 0 ? mv4.x : j == 1 ? mv4.y : j == 2 ? mv4.z : mv4.w;
      float r0 = __builtin_amdgcn_rcpf(1.0f + exp2_fast(u + w0));
      float r1 = __builtin_amdgcn_rcpf(1.0f + exp2_fast(u + w1));
      acc0 = fmaf(mv, r0, acc0);
      acc1 = fmaf(mv, r1, acc1);
    }
  }
  acc0 += __shfl_xor(acc0, 32);
  acc1 += __shfl_xor(acc1, 32);
  if (lane < 32) { e_s[0][e] = acc0; e_s[1][e] = acc1; }
  __syncthreads();

  // ---- phase 2: softmax (threads 0-255 -> t0, 256-511 -> t1) ----
  int t = tid >> 8, col = tid & 255;
  float x = e_s[t][col];
  float m = x;
#pragma unroll
  for (int off = 32; off; off >>= 1) m = fmaxf(m, __shfl_xor(m, off));
  if (lane == 0) redm[t][w & 3] = m;
  __syncthreads();
  m = fmaxf(fmaxf(redm[t][0], redm[t][1]), fmaxf(redm[t][2], redm[t][3]));
  float p = __expf(x - m);
  float s = p;
#pragma unroll
  for (int off = 32; off; off >>= 1) s += __shfl_xor(s, off);
  if (lane == 0) reds[t][w & 3] = s;
  __syncthreads();
  s = reds[t][0] + reds[t][1] + reds[t][2] + reds[t][3];
  float a = p * __builtin_amdgcn_rcpf(s);
  att2[col * 2 + t] = a;
  out_attn[(size_t)(b * TD_ + t0 + t) * TE_ + col] = a;
  __syncthreads();

  // ---- phase 3: context (thread owns column d = tid, both t rows) ----
  const float* enc_b = enc + (size_t)b * TE_ * DE_;
  float c0 = 0.f, c1 = 0.f;
#pragma unroll 4
  for (int ee = 0; ee < TE_; ++ee) {
    float2 av = *(const float2*)&att2[ee * 2];
    float xv = enc_b[(size_t)ee * DE_ + tid];
    c0 = fmaf(av.x, xv, c0);
    c1 = fmaf(av.y, xv, c1);
  }
  float* ctx0 = out_ctx + (size_t)(b * TD_ + t0) * DE_;
  ctx0[tid]       = c0;
  ctx0[DE_ + tid] = c1;
}

extern "C" void kernel_launch(void* const* d_in, const int* in_sizes, int n_in,
                              void* d_out, int out_size, void* d_ws, size_t ws_size,
                              hipStream_t stream) {
  const float* enc = (const float*)d_in[0];
  const float* dec = (const float*)d_in[1];
  const float* Ua  = (const float*)d_in[2];
  const float* Wa  = (const float*)d_in[3];
  const float* Va  = (const float*)d_in[4];

  float* out_ctx  = (float*)d_out;                     // [B,TD,DE]
  float* out_attn = out_ctx + (size_t)B_ * TD_ * DE_;  // [B,TD,TE]

  char* wsp = (char*)d_ws;
  float* UhT = (float*)wsp;             wsp += (size_t)B_ * DE_ * TE_ * 4;  // [B][512 d][256 e]
  float* Wsm = (float*)wsp;             wsp += (size_t)B_ * TD_ * DE_ * 4;  // [B*256 t][512 d]
  ushort* ehi = (ushort*)wsp;           wsp += (size_t)B_ * TE_ * DE_ * 2;
  ushort* elo = (ushort*)wsp;           wsp += (size_t)B_ * TE_ * DE_ * 2;
  ushort* dhi = (ushort*)wsp;           wsp += (size_t)B_ * TD_ * DE_ * 2;
  ushort* dlo = (ushort*)wsp;           wsp += (size_t)B_ * TD_ * DE_ * 2;
  ushort* uhi = (ushort*)wsp;           wsp += (size_t)K_ * DE_ * 2;
  ushort* ulo = (ushort*)wsp;           wsp += (size_t)K_ * DE_ * 2;
  ushort* whi = (ushort*)wsp;           wsp += (size_t)K_ * DE_ * 2;
  ushort* wlo = (ushort*)wsp;           wsp += (size_t)K_ * DE_ * 2;

  conv_hilo<<<dim3(512, 2), 256, 0, stream>>>(enc, dec, ehi, elo, dhi, dlo);
  conv_bt<<<dim3(8, 8, 2), 256, 0, stream>>>(Ua, Wa, uhi, ulo, whi, wlo);
  gemm_mfma<<<dim3(512, 1, 2), 256, 0, stream>>>(
      ehi, elo, dhi, dlo, uhi, ulo, whi, wlo, UhT, Wsm);
  fused_attn<<<512, 512, 0, stream>>>(enc, UhT, Wsm, Va, out_ctx, out_attn);
}